// Round 1
// baseline (509.067 us; speedup 1.0000x reference)
//
#include <hip/hip_runtime.h>
#include <hip/hip_bf16.h>

// Gumbel 2:4 masked linear:  out = x @ (W * mask)^T + bias
//   x: [2,2048,4096] f32, W: [4096,4096] f32, bias: [4096] f32
//   mask from argmax over 6 patterns per 4-weight block (gumbel+choice logits)
// Strategy: quantize x and masked-W to bf16, run m97-style MFMA GEMM (fp32 acc).
// Workspace: 2 * 4096*4096 * 2B = 64 MiB (xq then wq).

#define K_DIM 4096
#define N_DIM 4096
#define M_DIM 4096

typedef unsigned short ushort_t;
typedef __attribute__((ext_vector_type(8))) __bf16 bf16x8;
typedef __attribute__((ext_vector_type(4))) float floatx4;

__device__ __forceinline__ unsigned f2bf(float f) {
    union { float f; unsigned u; } v; v.f = f;
    unsigned u = v.u;
    return (u + 0x7fffu + ((u >> 16) & 1u)) >> 16;   // RNE
}

// ---------------- x fp32 -> bf16 (8 elems/thread) ----------------
__global__ __launch_bounds__(256) void cvt_x_kernel(
    const float4* __restrict__ x4, uint4* __restrict__ xq4) {
    int t = blockIdx.x * 256 + threadIdx.x;          // 2,097,152 threads
    float4 a = x4[2 * t], b = x4[2 * t + 1];
    uint4 o;
    o.x = f2bf(a.x) | (f2bf(a.y) << 16);
    o.y = f2bf(a.z) | (f2bf(a.w) << 16);
    o.z = f2bf(b.x) | (f2bf(b.y) << 16);
    o.w = f2bf(b.z) | (f2bf(b.w) << 16);
    xq4[t] = o;
}

// ---------------- argmax mask + W fp32 -> masked bf16 ----------------
// patterns packed 4 bits each, idx0 at bits[3:0]: bit i = pattern[idx][i]
//   0:0011->0xC  1:0101->0xA  2:0110->0x6  3:1001->0x9  4:1010->0x5  5:1100->0x3
#define PAT_PACKED 0x3596ACu

__global__ __launch_bounds__(256) void mask_w_kernel(
    const float4* __restrict__ w4, const float4* __restrict__ cw4,
    const float4* __restrict__ gn4, uint4* __restrict__ wq4) {
    int t = blockIdx.x * 256 + threadIdx.x;          // handles 2 pattern-blocks
    float4 g0 = gn4[3 * t], g1 = gn4[3 * t + 1], g2 = gn4[3 * t + 2];
    float4 c0 = cw4[3 * t], c1 = cw4[3 * t + 1], c2 = cw4[3 * t + 2];
    float va[6] = {g0.x + c0.x, g0.y + c0.y, g0.z + c0.z,
                   g0.w + c0.w, g1.x + c1.x, g1.y + c1.y};
    float vb[6] = {g1.z + c1.z, g1.w + c1.w, g2.x + c2.x,
                   g2.y + c2.y, g2.z + c2.z, g2.w + c2.w};
    int ia = 0, ib = 0;
    float ma = va[0], mb = vb[0];
#pragma unroll
    for (int i = 1; i < 6; i++) {                    // strict > : first-max (jnp.argmax)
        if (va[i] > ma) { ma = va[i]; ia = i; }
        if (vb[i] > mb) { mb = vb[i]; ib = i; }
    }
    unsigned pa = (PAT_PACKED >> (ia * 4)) & 0xF;
    unsigned pb = (PAT_PACKED >> (ib * 4)) & 0xF;
    float4 w0 = w4[2 * t], w1 = w4[2 * t + 1];
    uint4 o;
    o.x = ((pa & 1) ? f2bf(w0.x) : 0u) | (((pa >> 1) & 1) ? (f2bf(w0.y) << 16) : 0u);
    o.y = ((pa >> 2 & 1) ? f2bf(w0.z) : 0u) | (((pa >> 3) & 1) ? (f2bf(w0.w) << 16) : 0u);
    o.z = ((pb & 1) ? f2bf(w1.x) : 0u) | (((pb >> 1) & 1) ? (f2bf(w1.y) << 16) : 0u);
    o.w = ((pb >> 2 & 1) ? f2bf(w1.z) : 0u) | (((pb >> 3) & 1) ? (f2bf(w1.w) << 16) : 0u);
    wq4[t] = o;
}

// ---------------- bf16 GEMM, both operands K-major (C = A * B^T + bias) ------
// m97 recipe: 128x128 tile, BK=32, 256 thr (4 waves, 2x2), 4x4 16x16x32 MFMA/wave,
// global_load_lds width=16 staging (LDS = lane-contiguous, NO padding).
__device__ __forceinline__ void async16(const ushort_t* g, ushort_t* l) {
    __builtin_amdgcn_global_load_lds(
        (const __attribute__((address_space(1))) void*)g,
        (__attribute__((address_space(3))) void*)l, 16, 0, 0);
}

__global__ __launch_bounds__(256) void gemm_bt_kernel(
    const ushort_t* __restrict__ A,   // M x K bf16 (x)
    const ushort_t* __restrict__ B,   // N x K bf16 (masked W)
    const float* __restrict__ bias,
    float* __restrict__ C) {
    __shared__ ushort_t As[128 * 32];
    __shared__ ushort_t Bs[128 * 32];

    const int tid  = threadIdx.x;
    const int bm   = blockIdx.y * 128;
    const int bn   = blockIdx.x * 128;
    const int lane = tid & 63;
    const int wave = tid >> 6;
    const int wr   = (wave >> 1) * 64;      // wave row offset in tile
    const int wc   = (wave & 1) * 64;       // wave col offset in tile
    const int fr   = lane & 15;             // fragment row (A.m / B.n / D.col)
    const int q    = lane >> 4;             // quad -> k-slice (and D row base q*4)

    // staging: thread t loads 8 bf16 (16B): row = t>>2 (+64*c), koff = (t&3)*8
    const int srow  = tid >> 2;
    const int skoff = (tid & 3) * 8;
    const ushort_t* Ag0 = A + (size_t)(bm + srow) * K_DIM + skoff;
    const ushort_t* Ag1 = Ag0 + (size_t)64 * K_DIM;
    const ushort_t* Bg0 = B + (size_t)(bn + srow) * K_DIM + skoff;
    const ushort_t* Bg1 = Bg0 + (size_t)64 * K_DIM;
    ushort_t* lA0 = &As[tid * 8];
    ushort_t* lA1 = &As[2048 + tid * 8];
    ushort_t* lB0 = &Bs[tid * 8];
    ushort_t* lB1 = &Bs[2048 + tid * 8];

    floatx4 acc[4][4] = {};

    for (int kt = 0; kt < K_DIM; kt += 32) {
        __syncthreads();
        async16(Ag0 + kt, lA0);
        async16(Ag1 + kt, lA1);
        async16(Bg0 + kt, lB0);
        async16(Bg1 + kt, lB1);
        __syncthreads();

        bf16x8 a[4], b[4];
#pragma unroll
        for (int r = 0; r < 4; r++)
            a[r] = *(const bf16x8*)&As[(wr + r * 16 + fr) * 32 + q * 8];
#pragma unroll
        for (int c = 0; c < 4; c++)
            b[c] = *(const bf16x8*)&Bs[(wc + c * 16 + fr) * 32 + q * 8];
#pragma unroll
        for (int r = 0; r < 4; r++)
#pragma unroll
            for (int c = 0; c < 4; c++)
                acc[r][c] = __builtin_amdgcn_mfma_f32_16x16x32_bf16(
                    a[r], b[c], acc[r][c], 0, 0, 0);
    }

    // epilogue: D col = lane&15, row = q*4 + reg
#pragma unroll
    for (int r = 0; r < 4; r++) {
#pragma unroll
        for (int c = 0; c < 4; c++) {
            const int grow = bm + wr + r * 16 + q * 4;
            const int gcol = bn + wc + c * 16 + fr;
            const float bv = bias[gcol];
#pragma unroll
            for (int reg = 0; reg < 4; reg++)
                C[(size_t)(grow + reg) * N_DIM + gcol] = acc[r][c][reg] + bv;
        }
    }
}

extern "C" void kernel_launch(void* const* d_in, const int* in_sizes, int n_in,
                              void* d_out, int out_size, void* d_ws, size_t ws_size,
                              hipStream_t stream) {
    const float* x    = (const float*)d_in[0];
    const float* w    = (const float*)d_in[1];
    const float* bias = (const float*)d_in[2];
    const float* cw   = (const float*)d_in[3];
    const float* gn   = (const float*)d_in[4];
    ushort_t* xq = (ushort_t*)d_ws;                       // 32 MiB
    ushort_t* wq = xq + (size_t)M_DIM * K_DIM;            // 32 MiB
    float* out = (float*)d_out;

    cvt_x_kernel<<<8192, 256, 0, stream>>>((const float4*)x, (uint4*)xq);
    mask_w_kernel<<<8192, 256, 0, stream>>>((const float4*)w, (const float4*)cw,
                                            (const float4*)gn, (uint4*)wq);
    dim3 grid(N_DIM / 128, M_DIM / 128);
    gemm_bt_kernel<<<grid, 256, 0, stream>>>(xq, wq, bias, out);
}

// Round 2
// 490.732 us; speedup vs baseline: 1.0374x; 1.0374x over previous
//
#include <hip/hip_runtime.h>
#include <hip/hip_bf16.h>

// Gumbel 2:4 masked linear:  out = x @ (W * mask)^T + bias
// Round 2: (a) fused prep kernel with LDS-coalesced gumbel/choice loads,
//          (b) GEMM BK=64 superstep (half the barrier drains) with XOR-swizzled
//              LDS k-chunks to keep b128 reads at the m97 8-way-max level.

#define K_DIM 4096
#define N_DIM 4096
#define M_DIM 4096

typedef unsigned short ushort_t;
typedef __attribute__((ext_vector_type(8))) __bf16 bf16x8;
typedef __attribute__((ext_vector_type(4))) float floatx4;

__device__ __forceinline__ unsigned f2bf(float f) {
    union { float f; unsigned u; } v; v.f = f;
    unsigned u = v.u;
    return (u + 0x7fffu + ((u >> 16) & 1u)) >> 16;   // RNE
}

// patterns packed 4 bits each, idx0 at bits[3:0]: bit i = pattern[idx][i]
#define PAT_PACKED 0x3596ACu

// ---------------- fused prep ----------------
// blocks [0,8192): x fp32->bf16 (8 elems/thread, fully coalesced)
// blocks [8192,12288): per block, 1024 pattern-blocks:
//   stage (gn+cw) into LDS via coalesced float4, argmax from LDS, mask W->bf16
__global__ __launch_bounds__(256) void prep_kernel(
    const float4* __restrict__ x4, uint4* __restrict__ xq4,
    const float4* __restrict__ w4, const float4* __restrict__ cw4,
    const float4* __restrict__ gn4, uint2* __restrict__ wq2) {
    __shared__ float lsum[6144];                     // 1024 blocks x 6 logits = 24KB
    const int tid = threadIdx.x;

    if (blockIdx.x < 8192) {
        int t = blockIdx.x * 256 + tid;
        float4 a = x4[2 * t], b = x4[2 * t + 1];
        uint4 o;
        o.x = f2bf(a.x) | (f2bf(a.y) << 16);
        o.y = f2bf(a.z) | (f2bf(a.w) << 16);
        o.z = f2bf(b.x) | (f2bf(b.y) << 16);
        o.w = f2bf(b.z) | (f2bf(b.w) << 16);
        xq4[t] = o;
        return;
    }

    const int bb = blockIdx.x - 8192;                // [0,4096)
    const float4* g4 = gn4 + (size_t)bb * 1536;
    const float4* c4 = cw4 + (size_t)bb * 1536;
    float4* l4 = (float4*)lsum;
#pragma unroll
    for (int j = 0; j < 6; j++) {                    // coalesced: lane-consecutive float4
        float4 g = g4[j * 256 + tid], c = c4[j * 256 + tid];
        float4 s;
        s.x = g.x + c.x; s.y = g.y + c.y; s.z = g.z + c.z; s.w = g.w + c.w;
        l4[j * 256 + tid] = s;
    }
    __syncthreads();

#pragma unroll
    for (int sub = 0; sub < 4; sub++) {
        const int pb = sub * 256 + tid;              // local pattern-block
        const float2* lp = (const float2*)&lsum[pb * 6];   // 24B-> always 8B aligned
        float2 v0 = lp[0], v1 = lp[1], v2 = lp[2];
        float v[6] = {v0.x, v0.y, v1.x, v1.y, v2.x, v2.y};
        int idx = 0; float m = v[0];
#pragma unroll
        for (int i = 1; i < 6; i++)                  // strict > : first-max (jnp.argmax)
            if (v[i] > m) { m = v[i]; idx = i; }
        const unsigned p = (PAT_PACKED >> (idx * 4)) & 0xF;
        const float4 w = w4[(size_t)bb * 1024 + pb]; // coalesced
        uint2 o;
        o.x = ((p & 1) ? f2bf(w.x) : 0u) | (((p >> 1) & 1) ? (f2bf(w.y) << 16) : 0u);
        o.y = (((p >> 2) & 1) ? f2bf(w.z) : 0u) | (((p >> 3) & 1) ? (f2bf(w.w) << 16) : 0u);
        wq2[(size_t)bb * 1024 + pb] = o;             // coalesced
    }
}

// ---------------- bf16 GEMM, C = A * B^T + bias, BK=64 superstep ----------------
// 128x128 tile, 256 thr (4 waves 2x2), 4x4 16x16x32 MFMA per wave per 32-k half.
// LDS logical layout As[row][chunk] (chunk = 8 bf16 = 16B), physical chunk index
// XOR-swizzled by (row&7) so b128 frag reads keep 8 distinct bank groups.
// global_load_lds dest is lane-linear (wave-uniform base + lane*16B) as required;
// the swizzle is applied on the *global source* address instead.
__device__ __forceinline__ void async16(const ushort_t* g, ushort_t* l) {
    __builtin_amdgcn_global_load_lds(
        (const __attribute__((address_space(1))) void*)g,
        (__attribute__((address_space(3))) void*)l, 16, 0, 0);
}

__global__ __launch_bounds__(256) void gemm_bt_kernel(
    const ushort_t* __restrict__ A,   // M x K bf16 (x)
    const ushort_t* __restrict__ B,   // N x K bf16 (masked W)
    const float* __restrict__ bias,
    float* __restrict__ C) {
    __shared__ ushort_t As[128 * 64];                // 16KB
    __shared__ ushort_t Bs[128 * 64];                // 16KB

    const int tid  = threadIdx.x;
    const int bm   = blockIdx.y * 128;
    const int bn   = blockIdx.x * 128;
    const int lane = tid & 63;
    const int wave = tid >> 6;
    const int wr   = (wave >> 1) * 64;
    const int wc   = (wave & 1) * 64;
    const int fr   = lane & 15;
    const int q    = lane >> 4;
    const int f7   = fr & 7;

    // staging: slot s = i*256+tid holds global chunk ((s&7) ^ (row&7)) of row s>>3
    const int rA  = tid >> 3;                        // row within 32-row group
    const int swz = (tid & 7) ^ (rA & 7);            // i-invariant (i*32 ≡ 0 mod 8)
    const ushort_t* Ag = A + (size_t)(bm + rA) * K_DIM + swz * 8;
    const ushort_t* Bg = B + (size_t)(bn + rA) * K_DIM + swz * 8;
    ushort_t* lA = &As[tid * 8];
    ushort_t* lB = &Bs[tid * 8];

    floatx4 acc[4][4] = {};

    for (int kt = 0; kt < K_DIM; kt += 64) {
        __syncthreads();
#pragma unroll
        for (int i = 0; i < 4; i++) {
            async16(Ag + (size_t)i * 32 * K_DIM + kt, lA + i * 2048);
            async16(Bg + (size_t)i * 32 * K_DIM + kt, lB + i * 2048);
        }
        __syncthreads();

#pragma unroll
        for (int h = 0; h < 2; h++) {
            bf16x8 a[4], b[4];
#pragma unroll
            for (int r = 0; r < 4; r++) {
                const int row = wr + r * 16 + fr;
                a[r] = *(const bf16x8*)&As[row * 64 + (((h * 4 + q) ^ f7) * 8)];
            }
#pragma unroll
            for (int c = 0; c < 4; c++) {
                const int row = wc + c * 16 + fr;
                b[c] = *(const bf16x8*)&Bs[row * 64 + (((h * 4 + q) ^ f7) * 8)];
            }
#pragma unroll
            for (int r = 0; r < 4; r++)
#pragma unroll
                for (int c = 0; c < 4; c++)
                    acc[r][c] = __builtin_amdgcn_mfma_f32_16x16x32_bf16(
                        a[r], b[c], acc[r][c], 0, 0, 0);
        }
    }

    // epilogue: D col = lane&15, row = q*4 + reg
#pragma unroll
    for (int r = 0; r < 4; r++) {
#pragma unroll
        for (int c = 0; c < 4; c++) {
            const int grow = bm + wr + r * 16 + q * 4;
            const int gcol = bn + wc + c * 16 + fr;
            const float bv = bias[gcol];
#pragma unroll
            for (int reg = 0; reg < 4; reg++)
                C[(size_t)(grow + reg) * N_DIM + gcol] = acc[r][c][reg] + bv;
        }
    }
}

extern "C" void kernel_launch(void* const* d_in, const int* in_sizes, int n_in,
                              void* d_out, int out_size, void* d_ws, size_t ws_size,
                              hipStream_t stream) {
    const float* x    = (const float*)d_in[0];
    const float* w    = (const float*)d_in[1];
    const float* bias = (const float*)d_in[2];
    const float* cw   = (const float*)d_in[3];
    const float* gn   = (const float*)d_in[4];
    ushort_t* xq = (ushort_t*)d_ws;                       // 32 MiB
    ushort_t* wq = xq + (size_t)M_DIM * K_DIM;            // 32 MiB
    float* out = (float*)d_out;

    prep_kernel<<<12288, 256, 0, stream>>>(
        (const float4*)x, (uint4*)xq, (const float4*)w,
        (const float4*)cw, (const float4*)gn, (uint2*)wq);
    dim3 grid(N_DIM / 128, M_DIM / 128);
    gemm_bt_kernel<<<grid, 256, 0, stream>>>(xq, wq, bias, out);
}